// Round 4
// baseline (61.350 us; speedup 1.0000x reference)
//
#include <hip/hip_runtime.h>

// Depth-4 path signature, C=10, L=64, B=2048.
// R3: lane-local formulation (zero barriers, zero cross-lane traffic in main
// loop), plain-C math so the register allocator keeps accumulators in VGPRs
// (R2's inline-asm "v" constraints caused AGPR<->VGPR thrash: VGPR_Count=72
// with ~150 live floats). One batch elem per 128-thread block, grid=2048.
// Each lane owns one (i,j): s1=S1[i], s2=S2[ij], s3[5]=S3[ij,:] (f2 pairs),
// s4[50]=S4[ij,:,:] (f2 pairs). Horner Chen step (verified R0-R2):
//   u1=s1+di/4; v1=s1+di/3; w1=s1+di/2
//   u2=s2+u1*dj/3; v2=s2+v1*dj/2; s2+=w1*dj; s1+=di
//   u3[k]=s3[k]+u2*dk/2; s3[k]+=v2*dk; s4[k][l]+=u3[k]*dl

typedef float f2 __attribute__((ext_vector_type(2)));
typedef float f4 __attribute__((ext_vector_type(4)));

constexpr int C = 10;
constexpr int L = 64;
constexpr int NSTEP = L - 1;                   // 63
constexpr int OUTSZ = 10 + 100 + 1000 + 10000; // 11110
constexpr int ROWP = 12;                       // padded dx row stride

__device__ __forceinline__ f2 fma2(f2 a, f2 b, f2 c) {
  return f2{fmaf(a.x, b.x, c.x), fmaf(a.y, b.y, c.y)};
}

__global__ __launch_bounds__(128) void sig4_kernel(
    const float* __restrict__ x, float* __restrict__ out)
{
  const int t = threadIdx.x;

  __shared__ float dxs[NSTEP * ROWP];  // [63][12] padded rows (16B-aligned)
  __shared__ float pl[C * L];          // staged path (prologue only)

  const float* __restrict__ xb = x + (size_t)blockIdx.x * (C * L);
  for (int i = t; i < C * L; i += 128) pl[i] = xb[i];
  __syncthreads();
  for (int i = t; i < NSTEP * C; i += 128) {
    int s = i / C, c = i - s * C;
    dxs[s * ROWP + c] = pl[c * L + s + 1] - pl[c * L + s];
  }
  __syncthreads();

  const int p = (t < 100) ? t : 0;   // clamp idle lanes (no divergence)
  const int ii = p / 10;
  const int jj = p - ii * 10;

  float s1 = 0.f, s2 = 0.f;
  f2 s3[5];
  f2 s4[50];                         // row k=2kp+r -> s4[(2kp+r)*5+m], l=2m,2m+1
  #pragma unroll
  for (int k = 0; k < 5; ++k) s3[k] = f2{0.f, 0.f};
  #pragma unroll
  for (int m = 0; m < 50; ++m) s4[m] = f2{0.f, 0.f};

  const float* row = dxs;
  for (int s = 0; s < NSTEP; ++s, row += ROWP) {
    f4 a = *(const f4*)row;          // wave-uniform broadcast reads
    f4 bb = *(const f4*)(row + 4);
    f2 cc = *(const f2*)(row + 8);
    f2 dp0 = {a.x, a.y}, dp1 = {a.z, a.w};
    f2 dp2 = {bb.x, bb.y}, dp3 = {bb.z, bb.w}, dp4 = cc;
    float di = row[ii];              // scattered, 10 banks, conflict-free
    float dj = row[jj];

    float u1 = fmaf(di, 0.25f, s1);
    float v1 = fmaf(di, (1.f / 3.f), s1);
    float w1 = fmaf(di, 0.5f, s1);
    float u2 = fmaf(u1, dj * (1.f / 3.f), s2);
    float v2 = fmaf(v1, dj * 0.5f, s2);
    s2 = fmaf(w1, dj, s2);
    s1 += di;

    f2 uvx = {u2 * 0.5f, u2 * 0.5f};
    f2 uvy = {v2, v2};
    f2 dpl[5] = {dp0, dp1, dp2, dp3, dp4};
    #pragma unroll
    for (int kp = 0; kp < 5; ++kp) {
      f2 u3 = fma2(uvx, dpl[kp], s3[kp]);
      s3[kp] = fma2(uvy, dpl[kp], s3[kp]);
      f2 u3lo = {u3.x, u3.x};
      f2 u3hi = {u3.y, u3.y};
      #pragma unroll
      for (int m = 0; m < 5; ++m) {
        s4[(2 * kp) * 5 + m]     = fma2(u3lo, dpl[m], s4[(2 * kp) * 5 + m]);
        s4[(2 * kp + 1) * 5 + m] = fma2(u3hi, dpl[m], s4[(2 * kp + 1) * 5 + m]);
      }
    }
  }

  // ---- epilogue: each lane stores its own slices (8B-aligned f2 stores) ----
  if (t < 100) {
    float* __restrict__ ob = out + (size_t)blockIdx.x * OUTSZ;
    if (jj == 0) ob[ii] = s1;              // level 1
    ob[10 + t] = s2;                       // level 2
    #pragma unroll
    for (int kp = 0; kp < 5; ++kp)         // level 3: 110 + p*10 + k
      *(f2*)(ob + 110 + t * 10 + 2 * kp) = s3[kp];
    #pragma unroll
    for (int m = 0; m < 50; ++m)           // level 4: 1110 + p*100 + kl
      *(f2*)(ob + 1110 + t * 100 + 2 * m) = s4[m];
  }
}

extern "C" void kernel_launch(void* const* d_in, const int* in_sizes, int n_in,
                              void* d_out, int out_size, void* d_ws, size_t ws_size,
                              hipStream_t stream) {
  const float* x = (const float*)d_in[0];
  float* out = (float*)d_out;
  const int batch = in_sizes[0] / (C * L);   // 2048
  sig4_kernel<<<dim3(batch), dim3(128), 0, stream>>>(x, out);
}

// Round 5
// 61.255 us; speedup vs baseline: 1.0016x; 1.0016x over previous
//
#include <hip/hip_runtime.h>

// Depth-4 path signature, C=10, L=64, B=2048.
// R4: lane-local (zero barriers in main loop), one elem per 128-thr block.
// Each lane owns (i,j): s1=S1[i], s2=S2[ij], s3[5] f2 = S3[ij,:],
// s4[50] f2 = S4[ij,:,:]. Horner Chen step (verified R0-R3):
//   u1=s1+di/4; v1=s1+di/3; w1=s1+di/2
//   u2=s2+u1*dj/3; v2=s2+v1*dj/2; s2+=w1*dj; s1+=di
//   u3[k]=s3[k]+u2*dk/2; s3[k]+=v2*dk; s4[k][l]+=u3[k]*dl
// vs R3: (1) __builtin_elementwise_fma on f2 -> v_pk_fma_f32 (R3's fmaf
// pairs did NOT fuse: VALU-busy time showed ~162 insts/step, unpacked);
// (2) 2-step software pipeline of the dx-row LDS reads (A/B registers,
// all-static indexing) to hide LDS latency at low occupancy.

typedef float f2 __attribute__((ext_vector_type(2)));
typedef float f4 __attribute__((ext_vector_type(4)));

constexpr int C = 10;
constexpr int L = 64;
constexpr int NSTEP = L - 1;                   // 63
constexpr int OUTSZ = 10 + 100 + 1000 + 10000; // 11110
constexpr int ROWP = 12;                       // padded dx row stride

struct Row {
  f2 d[5];
  float di, dj;
};

__device__ __forceinline__ void load_row(const float* __restrict__ row,
                                         int ii, int jj, Row& r) {
  f4 a = *(const f4*)row;
  f4 b = *(const f4*)(row + 4);
  f2 c = *(const f2*)(row + 8);
  r.d[0] = f2{a.x, a.y};
  r.d[1] = f2{a.z, a.w};
  r.d[2] = f2{b.x, b.y};
  r.d[3] = f2{b.z, b.w};
  r.d[4] = c;
  r.di = row[ii];   // 10 distinct words, 10 banks: conflict-free
  r.dj = row[jj];
}

__global__ __launch_bounds__(128) void sig4_kernel(
    const float* __restrict__ x, float* __restrict__ out)
{
  const int t = threadIdx.x;

  __shared__ float dxs[NSTEP * ROWP];  // [63][12] padded rows
  __shared__ float pl[C * L];          // staged path (prologue only)

  const float* __restrict__ xb = x + (size_t)blockIdx.x * (C * L);
  for (int i = t; i < C * L; i += 128) pl[i] = xb[i];
  __syncthreads();
  for (int i = t; i < NSTEP * C; i += 128) {
    int s = i / C, c = i - s * C;
    dxs[s * ROWP + c] = pl[c * L + s + 1] - pl[c * L + s];
  }
  __syncthreads();

  const int p = (t < 100) ? t : 0;     // clamp idle lanes
  const int ii = p / 10;
  const int jj = p - ii * 10;

  float s1 = 0.f, s2 = 0.f;
  f2 s3[5];
  f2 s4[50];   // row k=2kp+r -> s4[(2kp+r)*5+m], covering l=2m,2m+1
  #pragma unroll
  for (int k = 0; k < 5; ++k) s3[k] = f2{0.f, 0.f};
  #pragma unroll
  for (int m = 0; m < 50; ++m) s4[m] = f2{0.f, 0.f};

  auto step = [&](const Row& r) {
    float u1 = fmaf(r.di, 0.25f, s1);
    float v1 = fmaf(r.di, (1.f / 3.f), s1);
    float w1 = fmaf(r.di, 0.5f, s1);
    float u2 = fmaf(u1, r.dj * (1.f / 3.f), s2);
    float v2 = fmaf(v1, r.dj * 0.5f, s2);
    s2 = fmaf(w1, r.dj, s2);
    s1 += r.di;
    float u2h = u2 * 0.5f;
    f2 u2v = {u2h, u2h};
    f2 v2v = {v2, v2};
    #pragma unroll
    for (int kp = 0; kp < 5; ++kp) {
      f2 u3 = __builtin_elementwise_fma(u2v, r.d[kp], s3[kp]);
      s3[kp] = __builtin_elementwise_fma(v2v, r.d[kp], s3[kp]);
      f2 u3lo = {u3.x, u3.x};
      f2 u3hi = {u3.y, u3.y};
      #pragma unroll
      for (int m = 0; m < 5; ++m) {
        s4[(2 * kp) * 5 + m] =
            __builtin_elementwise_fma(u3lo, r.d[m], s4[(2 * kp) * 5 + m]);
        s4[(2 * kp + 1) * 5 + m] =
            __builtin_elementwise_fma(u3hi, r.d[m], s4[(2 * kp + 1) * 5 + m]);
      }
    }
  };

  Row A, B;
  load_row(dxs, ii, jj, A);
  // 2-step software pipeline: LDS load of next row overlaps current math.
  for (int s = 0; s < NSTEP - 1; s += 2) {        // s = 0,2,...,60
    load_row(dxs + (s + 1) * ROWP, ii, jj, B);
    step(A);
    load_row(dxs + (s + 2) * ROWP, ii, jj, A);    // row <= 62: always valid
    step(B);
  }
  step(A);                                        // step 62

  // ---- epilogue: each lane stores its own slices (8B-aligned f2) ----
  if (t < 100) {
    float* __restrict__ ob = out + (size_t)blockIdx.x * OUTSZ;
    if (jj == 0) ob[ii] = s1;              // level 1
    ob[10 + t] = s2;                       // level 2
    #pragma unroll
    for (int kp = 0; kp < 5; ++kp)         // level 3: 110 + p*10 + k
      *(f2*)(ob + 110 + t * 10 + 2 * kp) = s3[kp];
    #pragma unroll
    for (int m = 0; m < 50; ++m)           // level 4: 1110 + p*100 + kl
      *(f2*)(ob + 1110 + t * 100 + 2 * m) = s4[m];
  }
}

extern "C" void kernel_launch(void* const* d_in, const int* in_sizes, int n_in,
                              void* d_out, int out_size, void* d_ws, size_t ws_size,
                              hipStream_t stream) {
  const float* x = (const float*)d_in[0];
  float* out = (float*)d_out;
  const int batch = in_sizes[0] / (C * L);   // 2048
  sig4_kernel<<<dim3(batch), dim3(128), 0, stream>>>(x, out);
}